// Round 10
// baseline (522.610 us; speedup 1.0000x reference)
//
#include <hip/hip_runtime.h>
#include <hip/hip_cooperative_groups.h>
#include <hip/hip_bf16.h>
#include <math.h>

namespace cg = cooperative_groups;

#define Hh 1024
#define Vv 50257
#define Ll 2048
#define H2 2048
#define H4 4096

// ws float offsets
#define WS_EMB  0
#define WS_CTX  3072
#define WS_LOG  9216
#define WS_PAIR 59474
// packed bf16 regions (byte offsets)
#define OA_BYTES 245760u     // A_pk: 2048x2048 bf16 = 8 MB
#define OB_BYTES 8634368u    // B_pk: 2048x1024 bf16 = 4 MB
// partial logits: 16 rows x PP floats
#define PP 50264
#define WS_PART_F 3210240
// hbias partials: 64 rows x 1024 floats
#define WS_HBP 4014464
// score partials: 16 rows x 2048 floats
#define WS_SCP 4080000
// gate partials: 128 rows x 1024 floats
#define WS_GATEP 4112768

// d_out layout: [log_softmax 50257][next_hidden 1024][attn_weights 2048][new_cell 1024]
#define OUT_NH Vv
#define OUT_AW (Vv + 1024)
#define OUT_NC (Vv + 3072)

typedef __attribute__((ext_vector_type(8))) short bf16x8;
typedef __attribute__((ext_vector_type(4))) float f32x4;
typedef __attribute__((ext_vector_type(4), aligned(4))) float f32x4u;

__device__ __forceinline__ float sigmoidf_(float x) { return 1.f / (1.f + expf(-x)); }
__device__ __forceinline__ unsigned short f2bf(float f) {
    union { float f; unsigned u; } v; v.f = f;
    unsigned r = v.u + 0x7FFF + ((v.u >> 16) & 1);
    return (unsigned short)(r >> 16);
}

// stream one (kc, vb) chunk of W_out: 256 k x 4 v per thread, 8 indep chains
__device__ __forceinline__ void stream_wout(const float* __restrict__ W_out,
        const float* __restrict__ xs, int k0, int v4, float* __restrict__ part_row) {
    if (v4 + 3 < Vv) {
        const char* p = (const char*)(W_out + (size_t)k0 * Vv + v4);
        const size_t st = (size_t)Vv * 4;
        f32x4 a0 = (f32x4){0.f,0.f,0.f,0.f}, a1 = a0, a2 = a0, a3 = a0;
        f32x4 a4 = a0, a5 = a0, a6 = a0, a7 = a0;
        for (int i = 0; i < 256; i += 8) {
            f32x4u w0 = __builtin_nontemporal_load((const f32x4u*)(p));
            f32x4u w1 = __builtin_nontemporal_load((const f32x4u*)(p + st));
            f32x4u w2 = __builtin_nontemporal_load((const f32x4u*)(p + 2 * st));
            f32x4u w3 = __builtin_nontemporal_load((const f32x4u*)(p + 3 * st));
            f32x4u w4 = __builtin_nontemporal_load((const f32x4u*)(p + 4 * st));
            f32x4u w5 = __builtin_nontemporal_load((const f32x4u*)(p + 5 * st));
            f32x4u w6 = __builtin_nontemporal_load((const f32x4u*)(p + 6 * st));
            f32x4u w7 = __builtin_nontemporal_load((const f32x4u*)(p + 7 * st));
            a0 += w0 * xs[i];     a1 += w1 * xs[i + 1];
            a2 += w2 * xs[i + 2]; a3 += w3 * xs[i + 3];
            a4 += w4 * xs[i + 4]; a5 += w5 * xs[i + 5];
            a6 += w6 * xs[i + 6]; a7 += w7 * xs[i + 7];
            p += 8 * st;
        }
        f32x4 a = ((a0 + a1) + (a2 + a3)) + ((a4 + a5) + (a6 + a7));
        __builtin_nontemporal_store(a, (f32x4u*)(part_row + v4));
    } else if (v4 < Vv) {
        for (int jj = 0; jj < 4 && v4 + jj < Vv; ++jj) {
            const float* p = W_out + (size_t)k0 * Vv + v4 + jj;
            float a = 0.f;
            for (int i = 0; i < 256; ++i) { a += xs[i] * (*p); p += Vv; }
            part_row[v4 + jj] = a;
        }
    }
}

// =========================== cooperative mega-kernel ===========================
__global__ __launch_bounds__(256, 2) void coopK(
        const int* __restrict__ tok, const float* __restrict__ hidden,
        const float* __restrict__ enc, const float* __restrict__ cell,
        const float* __restrict__ W_emb, const float* __restrict__ b_emb,
        const float* __restrict__ W_attn, const float* __restrict__ b_attn,
        const float* __restrict__ Wao,
        const float* __restrict__ Wgi, const float* __restrict__ bgi,
        const float* __restrict__ Wgo, const float* __restrict__ bgo,
        const float* __restrict__ Wgf, const float* __restrict__ bgf,
        const float* __restrict__ Wgc, const float* __restrict__ bgc,
        const float* __restrict__ W_out, const float* __restrict__ b_out,
        float* __restrict__ out, float* __restrict__ ws, char* __restrict__ wsb) {
    cg::grid_group gg = cg::this_grid();
    __shared__ float s1[2176];
    int bx = blockIdx.x, t = threadIdx.x;

    // ---------------- phase 1: free-half stream (0..399) | prep (400..511) ----
    if (bx < 400) {
        int kc = bx / 50, vb = bx % 50;          // kc 0..7: emb+hidden
        int k0 = kc * 256;
        int k = k0 + t;
        s1[t] = (k < 1024) ? (W_emb[(size_t)tok[0] * Hh + k] + b_emb[k]) : hidden[k - 1024];
        __syncthreads();
        stream_wout(W_out, s1, k0, vb * 1024 + t * 4, ws + WS_PART_F + (size_t)kc * PP);
    } else {
        for (int u = bx - 400; u < 3340; u += 112) {
            __syncthreads();
            if (u < 2048) {
                // packA: enc -> A_pk bf16 fragment order
                int mt = u >> 4, kc = u & 15;
                float (*a)[132] = (float(*)[132])s1;
                int row = t >> 4, c8 = (t & 15) * 8;
                const float* src = enc + (size_t)(mt * 16 + row) * H2 + kc * 128 + c8;
                float4 v0 = *(const float4*)src;
                float4 v1 = *(const float4*)(src + 4);
                *(float4*)&a[row][c8] = v0;
                *(float4*)&a[row][c8 + 4] = v1;
                __syncthreads();
                int ktl = t >> 6, l = t & 63;
                int r2 = l & 15, k8 = (l >> 4) * 8;
                bf16x8 o;
#pragma unroll
                for (int j = 0; j < 8; ++j) o[j] = (short)f2bf(a[r2][ktl * 32 + k8 + j]);
                *(bf16x8*)(wsb + OA_BYTES + ((size_t)(mt * 64 + kc * 4 + ktl)) * 1024 + l * 16) = o;
            } else if (u < 3072) {
                // packB: W_attn[0:2048] -> B_pk
                int uu = u - 2048;
                int kt = uu >> 4, nc = uu & 15;
                float (*b)[68] = (float(*)[68])s1;
                int r = t >> 3, c8 = (t & 7) * 8;
                const float* src = W_attn + (size_t)(kt * 32 + r) * Hh + nc * 64 + c8;
                float4 v0 = *(const float4*)src;
                float4 v1 = *(const float4*)(src + 4);
                *(float4*)&b[r][c8] = v0;
                *(float4*)&b[r][c8 + 4] = v1;
                __syncthreads();
                int ntl = t >> 6, l = t & 63;
                int col = ntl * 16 + (l & 15), k8 = (l >> 4) * 8;
                bf16x8 o;
#pragma unroll
                for (int j = 0; j < 8; ++j) o[j] = (short)f2bf(b[k8 + j][col]);
                *(bf16x8*)(wsb + OB_BYTES + ((size_t)((nc * 4 + ntl) * 64 + kt)) * 1024 + l * 16) = o;
            } else if (u < 3328) {
                // hbias partials
                int uu = u - 3072;
                int hc = uu & 3, kc = uu >> 2;
                int h = hc * 256 + t;
                int k0 = kc * 16;
                const float* p = W_attn + (size_t)(H2 + k0) * Hh + h;
                float acc = 0.f;
#pragma unroll
                for (int k = 0; k < 16; ++k) { acc += hidden[k0 + k] * __builtin_nontemporal_load(p); p += Hh; }
                ws[WS_HBP + kc * 1024 + h] = acc;
            } else {
                int i = (u - 3328) * 256 + t;     // 12 units -> 3072
                if (i < 1024) ws[WS_EMB + i] = W_emb[(size_t)tok[0] * Hh + i] + b_emb[i];
                else          ws[WS_CTX + (i - 1024)] = 0.f;
            }
        }
    }
    gg.sync();

    // ---------------- phase 2: MFMA GEMM, all 512 blocks, 4 waves, 1 m-tile/wave
    {
        int bm = bx >> 4, bn = bx & 15;
        int w = t >> 6, l = t & 63;
        if (t < 64) {
            int n = bn * 64 + t;
            float a = b_attn[n];
#pragma unroll 16
            for (int kc = 0; kc < 64; ++kc) a += ws[WS_HBP + kc * 1024 + n];
            s1[t] = a;
        }
        __syncthreads();
        int mt0 = bm * 4 + w;
        int nt0 = bn * 4;
        const char* pa  = wsb + OA_BYTES + (size_t)mt0 * 65536 + l * 16;
        const char* pb0 = wsb + OB_BYTES + (size_t)(nt0)     * 65536 + l * 16;
        const char* pb1 = wsb + OB_BYTES + (size_t)(nt0 + 1) * 65536 + l * 16;
        const char* pb2 = wsb + OB_BYTES + (size_t)(nt0 + 2) * 65536 + l * 16;
        const char* pb3 = wsb + OB_BYTES + (size_t)(nt0 + 3) * 65536 + l * 16;

        f32x4 acc[4];
#pragma unroll
        for (int j = 0; j < 4; ++j) acc[j] = (f32x4){0.f, 0.f, 0.f, 0.f};
        bf16x8 As[4], Bs[4][4];
#define LOADK(s, kk) { int o_ = (kk) * 1024; \
    As[s] = *(const bf16x8*)(pa + o_); \
    Bs[s][0] = *(const bf16x8*)(pb0 + o_); Bs[s][1] = *(const bf16x8*)(pb1 + o_); \
    Bs[s][2] = *(const bf16x8*)(pb2 + o_); Bs[s][3] = *(const bf16x8*)(pb3 + o_); }
#define MFMAK(s) { \
    _Pragma("unroll") for (int nr = 0; nr < 4; ++nr) \
        acc[nr] = __builtin_amdgcn_mfma_f32_16x16x32_bf16(As[s], Bs[s][nr], acc[nr], 0, 0, 0); }
        LOADK(0, 0) LOADK(1, 1) LOADK(2, 2) LOADK(3, 3)
        for (int kt = 0; kt < 60; kt += 4) {
            MFMAK(0) LOADK(0, kt + 4)
            MFMAK(1) LOADK(1, kt + 5)
            MFMAK(2) LOADK(2, kt + 6)
            MFMAK(3) LOADK(3, kt + 7)
        }
        MFMAK(0) MFMAK(1) MFMAK(2) MFMAK(3)
#undef LOADK
#undef MFMAK
        float sp[4] = {0.f, 0.f, 0.f, 0.f};
        int nl = l & 15;
#pragma unroll
        for (int nr = 0; nr < 4; ++nr) {
            float hb = s1[nr * 16 + nl];
            float wo = Wao[bn * 64 + nr * 16 + nl];
#pragma unroll
            for (int r = 0; r < 4; ++r)
                sp[r] += tanhf(acc[nr][r] + hb) * wo;
        }
#pragma unroll
        for (int m = 1; m <= 8; m <<= 1)
#pragma unroll
            for (int r = 0; r < 4; ++r) sp[r] += __shfl_xor(sp[r], m, 64);
        if (nl == 0) {
            int mbase = bm * 64 + w * 16 + (l >> 4) * 4;
#pragma unroll
            for (int r = 0; r < 4; ++r)
                ws[WS_SCP + bn * 2048 + mbase + r] = sp[r];
        }
    }
    gg.sync();

    // ---------------- phase 3: softmax over score-partials + context (0..255) --
    if (bx < 256) {
        float* red = s1;
        float* wl  = s1 + 256;
        int jc = bx & 7, lc = bx >> 3;
        float s[8];
        float mx = -INFINITY;
#pragma unroll
        for (int i = 0; i < 8; ++i) {
            int m = i * 256 + t;
            float v = 0.f;
#pragma unroll
            for (int bn = 0; bn < 16; ++bn) v += ws[WS_SCP + bn * 2048 + m];
            s[i] = v;
            mx = fmaxf(mx, v);
        }
        red[t] = mx;
        __syncthreads();
        for (int off = 128; off > 0; off >>= 1) {
            if (t < off) red[t] = fmaxf(red[t], red[t + off]);
            __syncthreads();
        }
        float M = red[0];
        __syncthreads();
        float se = 0.f;
#pragma unroll
        for (int i = 0; i < 8; ++i) se += expf(s[i] - M);
        red[t] = se;
        __syncthreads();
        for (int off = 128; off > 0; off >>= 1) {
            if (t < off) red[t] += red[t + off];
            __syncthreads();
        }
        float invZ = 1.f / red[0];
        int l0 = lc * 64;
        if (t < 64) {
            int m = l0 + t;
            float v = 0.f;
#pragma unroll
            for (int bn = 0; bn < 16; ++bn) v += ws[WS_SCP + bn * 2048 + m];
            wl[t] = expf(v - M) * invZ;
        }
        __syncthreads();
        if (jc == 0 && t < 64) out[OUT_AW + l0 + t] = wl[t];
        int j = jc * 256 + t;
        float acc = 0.f;
#pragma unroll 8
        for (int i = 0; i < 64; ++i)
            acc += wl[i] * enc[(size_t)(l0 + i) * H2 + j];
        atomicAdd(&ws[WS_CTX + j], acc);
    }
    gg.sync();

    // ---------------- phase 4: context-half stream (0..399) | gates (400..511) -
    if (bx < 400) {
        int kc = 8 + bx / 50, vb = bx % 50;
        int k0 = kc * 256;
        s1[t] = ws[WS_CTX + k0 - 2048 + t];
        __syncthreads();
        stream_wout(W_out, s1, k0, vb * 1024 + t * 4, ws + WS_PART_F + (size_t)kc * PP);
    } else {
        for (int u = bx - 400; u < 128; u += 112) {
            int g = u & 3, kc = u >> 2;
            int k0 = kc * 128;
            const float* Wm = (g == 0) ? Wgi : (g == 1) ? Wgo : (g == 2) ? Wgf : Wgc;
            const f32x4* p = (const f32x4*)(Wm + (size_t)k0 * Hh) + t;
            f32x4 a = (f32x4){0.f, 0.f, 0.f, 0.f};
#pragma unroll 8
            for (int k = k0; k < k0 + 128; ++k) {
                float x = (k < 1024) ? ws[WS_EMB + k] : (k < 3072) ? ws[WS_CTX + (k - 1024)] : hidden[k - 3072];
                f32x4 wv = __builtin_nontemporal_load(p);
                a += wv * x;
                p += 256;
            }
            *(f32x4*)&ws[WS_GATEP + (size_t)(g * 32 + kc) * 1024 + t * 4] = a;
        }
    }
    gg.sync();

    // ---------------- phase 5: logit reduce+stats (0..196) | cell (197) --------
    if (bx < 197) {
        float* sm = s1;
        int v = bx * 256 + t;
        float x = -INFINITY;
        if (v < Vv) {
            x = b_out[v];
            const float* pp = ws + WS_PART_F + v;
#pragma unroll
            for (int kc = 0; kc < 16; ++kc) x += pp[(size_t)kc * PP];
            ws[WS_LOG + v] = x;
        }
        sm[t] = x;
        __syncthreads();
        for (int off = 128; off > 0; off >>= 1) {
            if (t < off) sm[t] = fmaxf(sm[t], sm[t + off]);
            __syncthreads();
        }
        float m = sm[0];
        __syncthreads();
        sm[t] = (v < Vv) ? expf(x - m) : 0.f;
        __syncthreads();
        for (int off = 128; off > 0; off >>= 1) {
            if (t < off) sm[t] += sm[t + off];
            __syncthreads();
        }
        if (t == 0) { ws[WS_PAIR + 2 * bx] = m; ws[WS_PAIR + 2 * bx + 1] = sm[0]; }
    } else if (bx == 197) {
#pragma unroll
        for (int r = 0; r < 4; ++r) {
            int h = t + r * 256;
            float gp[4];
#pragma unroll
            for (int g = 0; g < 4; ++g) {
                float s = 0.f;
#pragma unroll 8
                for (int kc = 0; kc < 32; ++kc)
                    s += ws[WS_GATEP + (size_t)(g * 32 + kc) * 1024 + h];
                gp[g] = s;
            }
            float ig = sigmoidf_(gp[0] + bgi[h]);
            float og = sigmoidf_(gp[1] + bgo[h]);
            float fg = sigmoidf_(gp[2] + bgf[h]);
            float cg = tanhf(gp[3] + bgc[h]);
            float nc = fg * cell[h] + ig * cg;
            out[OUT_NC + h] = nc;
            out[OUT_NH + h] = og * tanhf(nc);
        }
    }
    gg.sync();

    // ---------------- phase 6: combine pairs + write log_softmax (0..196) ------
    if (bx < 197) {
        float* sm = s1;
        float* ss = s1 + 256;
        float m = (t < 197) ? ws[WS_PAIR + 2 * t] : -INFINITY;
        float s = (t < 197) ? ws[WS_PAIR + 2 * t + 1] : 0.f;
        sm[t] = m;
        __syncthreads();
        for (int off = 128; off > 0; off >>= 1) {
            if (t < off) sm[t] = fmaxf(sm[t], sm[t + off]);
            __syncthreads();
        }
        float M = sm[0];
        ss[t] = s * expf(m - M);
        __syncthreads();
        for (int off = 128; off > 0; off >>= 1) {
            if (t < off) ss[t] += ss[t + off];
            __syncthreads();
        }
        float logZ = M + logf(ss[0]);
        int v = bx * 256 + t;
        if (v < Vv) out[v] = ws[WS_LOG + v] - logZ;
    }
}

// =========================== fallback kernels (r9 set) =========================
__global__ __launch_bounds__(256) void kPrep(const int* __restrict__ tok,
        const float* __restrict__ W_emb, const float* __restrict__ b_emb,
        const float* __restrict__ enc, const float* __restrict__ W_attn,
        const float* __restrict__ hidden, float* __restrict__ ws, char* __restrict__ wsb) {
    __shared__ union { float a[16][132]; float b[32][68]; } sh;
    int bx = blockIdx.x, t = threadIdx.x;
    if (bx < 2048) {
        int mt = bx >> 4, kc = bx & 15;
        {
            int row = t >> 4, c8 = (t & 15) * 8;
            const float* src = enc + (size_t)(mt * 16 + row) * H2 + kc * 128 + c8;
            float4 v0 = *(const float4*)src;
            float4 v1 = *(const float4*)(src + 4);
            *(float4*)&sh.a[row][c8] = v0;
            *(float4*)&sh.a[row][c8 + 4] = v1;
        }
        __syncthreads();
        int ktl = t >> 6, l = t & 63;
        int r2 = l & 15, k8 = (l >> 4) * 8;
        bf16x8 o;
#pragma unroll
        for (int j = 0; j < 8; ++j) o[j] = (short)f2bf(sh.a[r2][ktl * 32 + k8 + j]);
        *(bf16x8*)(wsb + OA_BYTES + ((size_t)(mt * 64 + kc * 4 + ktl)) * 1024 + l * 16) = o;
    } else if (bx < 3072) {
        int bxx = bx - 2048;
        int kt = bxx >> 4, nc = bxx & 15;
        {
            int r = t >> 3, c8 = (t & 7) * 8;
            const float* src = W_attn + (size_t)(kt * 32 + r) * Hh + nc * 64 + c8;
            float4 v0 = *(const float4*)src;
            float4 v1 = *(const float4*)(src + 4);
            *(float4*)&sh.b[r][c8] = v0;
            *(float4*)&sh.b[r][c8 + 4] = v1;
        }
        __syncthreads();
        int ntl = t >> 6, l = t & 63;
        int col = ntl * 16 + (l & 15), k8 = (l >> 4) * 8;
        bf16x8 o;
#pragma unroll
        for (int j = 0; j < 8; ++j) o[j] = (short)f2bf(sh.b[k8 + j][col]);
        *(bf16x8*)(wsb + OB_BYTES + ((size_t)((nc * 4 + ntl) * 64 + kt)) * 1024 + l * 16) = o;
    } else if (bx < 3328) {
        int bxx = bx - 3072;
        int hc = bxx & 3, kc = bxx >> 2;
        int h = hc * 256 + t;
        int k0 = kc * 16;
        const float* p = W_attn + (size_t)(H2 + k0) * Hh + h;
        float acc = 0.f;
#pragma unroll
        for (int k = 0; k < 16; ++k) { acc += hidden[k0 + k] * __builtin_nontemporal_load(p); p += Hh; }
        ws[WS_HBP + kc * 1024 + h] = acc;
    } else {
        int i = (bx - 3328) * 256 + t;
        if (i < 1024) ws[WS_EMB + i] = W_emb[(size_t)tok[0] * Hh + i] + b_emb[i];
        else          ws[WS_CTX + (i - 1024)] = 0.f;
    }
}

__global__ __launch_bounds__(128, 1) void kG(const char* __restrict__ wsb,
        const float* __restrict__ b_attn, const float* __restrict__ Wo,
        float* __restrict__ ws) {
    __shared__ float hbv[64];
    int bx = blockIdx.x, t = threadIdx.x;
    int bm = bx >> 4, bn = bx & 15;
    int w = t >> 6, l = t & 63;
    if (t < 64) {
        int n = bn * 64 + t;
        float a = b_attn[n];
#pragma unroll 16
        for (int kc = 0; kc < 64; ++kc) a += ws[WS_HBP + kc * 1024 + n];
        hbv[t] = a;
    }
    __syncthreads();
    int mt0 = bm * 4 + w * 2;
    int nt0 = bn * 4;
    const char* pa0 = wsb + OA_BYTES + (size_t)(mt0)     * 65536 + l * 16;
    const char* pa1 = wsb + OA_BYTES + (size_t)(mt0 + 1) * 65536 + l * 16;
    const char* pb0 = wsb + OB_BYTES + (size_t)(nt0)     * 65536 + l * 16;
    const char* pb1 = wsb + OB_BYTES + (size_t)(nt0 + 1) * 65536 + l * 16;
    const char* pb2 = wsb + OB_BYTES + (size_t)(nt0 + 2) * 65536 + l * 16;
    const char* pb3 = wsb + OB_BYTES + (size_t)(nt0 + 3) * 65536 + l * 16;
    f32x4 acc[2][4];
#pragma unroll
    for (int i = 0; i < 2; ++i)
#pragma unroll
        for (int j = 0; j < 4; ++j) acc[i][j] = (f32x4){0.f, 0.f, 0.f, 0.f};
    bf16x8 As[8][2], Bs[8][4];
#define LOADK(s, kk) { int o_ = (kk) * 1024; \
    As[s][0] = *(const bf16x8*)(pa0 + o_); As[s][1] = *(const bf16x8*)(pa1 + o_); \
    Bs[s][0] = *(const bf16x8*)(pb0 + o_); Bs[s][1] = *(const bf16x8*)(pb1 + o_); \
    Bs[s][2] = *(const bf16x8*)(pb2 + o_); Bs[s][3] = *(const bf16x8*)(pb3 + o_); }
#define MFMAK(s) { \
    _Pragma("unroll") for (int mr = 0; mr < 2; ++mr) \
    _Pragma("unroll") for (int nr = 0; nr < 4; ++nr) \
        acc[mr][nr] = __builtin_amdgcn_mfma_f32_16x16x32_bf16(As[s][mr], Bs[s][nr], acc[mr][nr], 0, 0, 0); }
    LOADK(0, 0) LOADK(1, 1) LOADK(2, 2) LOADK(3, 3)
    LOADK(4, 4) LOADK(5, 5) LOADK(6, 6) LOADK(7, 7)
    for (int kt = 0; kt < 56; kt += 8) {
        MFMAK(0) LOADK(0, kt + 8)
        MFMAK(1) LOADK(1, kt + 9)
        MFMAK(2) LOADK(2, kt + 10)
        MFMAK(3) LOADK(3, kt + 11)
        MFMAK(4) LOADK(4, kt + 12)
        MFMAK(5) LOADK(5, kt + 13)
        MFMAK(6) LOADK(6, kt + 14)
        MFMAK(7) LOADK(7, kt + 15)
    }
    MFMAK(0) MFMAK(1) MFMAK(2) MFMAK(3) MFMAK(4) MFMAK(5) MFMAK(6) MFMAK(7)
#undef LOADK
#undef MFMAK
    float sp[8];
#pragma unroll
    for (int i = 0; i < 8; ++i) sp[i] = 0.f;
    int nl = l & 15;
#pragma unroll
    for (int nr = 0; nr < 4; ++nr) {
        float hb = hbv[nr * 16 + nl];
        float wo = Wo[bn * 64 + nr * 16 + nl];
#pragma unroll
        for (int mr = 0; mr < 2; ++mr)
#pragma unroll
            for (int r = 0; r < 4; ++r)
                sp[mr * 4 + r] += tanhf(acc[mr][nr][r] + hb) * wo;
    }
#pragma unroll
    for (int m = 1; m <= 8; m <<= 1)
#pragma unroll
        for (int i = 0; i < 8; ++i) sp[i] += __shfl_xor(sp[i], m, 64);
    if ((l & 15) == 0) {
        int mbase = bm * 64 + w * 32 + (l >> 4) * 4;
#pragma unroll
        for (int mr = 0; mr < 2; ++mr)
#pragma unroll
            for (int r = 0; r < 4; ++r)
                ws[WS_SCP + bn * 2048 + mbase + mr * 16 + r] = sp[mr * 4 + r];
    }
}

__global__ __launch_bounds__(256) void k34(const float* __restrict__ enc,
        float* __restrict__ ws, float* __restrict__ out) {
    __shared__ float red[256];
    __shared__ float wl[64];
    int bx = blockIdx.x, t = threadIdx.x;
    int jc = bx & 7, lc = bx >> 3;
    float s[8];
    float mx = -INFINITY;
#pragma unroll
    for (int i = 0; i < 8; ++i) {
        int m = i * 256 + t;
        float v = 0.f;
#pragma unroll
        for (int bn = 0; bn < 16; ++bn) v += ws[WS_SCP + bn * 2048 + m];
        s[i] = v;
        mx = fmaxf(mx, v);
    }
    red[t] = mx;
    __syncthreads();
    for (int off = 128; off > 0; off >>= 1) {
        if (t < off) red[t] = fmaxf(red[t], red[t + off]);
        __syncthreads();
    }
    float M = red[0];
    __syncthreads();
    float se = 0.f;
#pragma unroll
    for (int i = 0; i < 8; ++i) se += expf(s[i] - M);
    red[t] = se;
    __syncthreads();
    for (int off = 128; off > 0; off >>= 1) {
        if (t < off) red[t] += red[t + off];
        __syncthreads();
    }
    float invZ = 1.f / red[0];
    int l0 = lc * 64;
    if (t < 64) {
        int m = l0 + t;
        float v = 0.f;
#pragma unroll
        for (int bn = 0; bn < 16; ++bn) v += ws[WS_SCP + bn * 2048 + m];
        wl[t] = expf(v - M) * invZ;
    }
    __syncthreads();
    if (jc == 0 && t < 64) out[OUT_AW + l0 + t] = wl[t];
    int j = jc * 256 + t;
    float acc = 0.f;
#pragma unroll 8
    for (int i = 0; i < 64; ++i)
        acc += wl[i] * enc[(size_t)(l0 + i) * H2 + j];
    atomicAdd(&ws[WS_CTX + j], acc);
}

__global__ __launch_bounds__(256) void kS(const float* __restrict__ W_out,
        const float* __restrict__ W_i, const float* __restrict__ W_o,
        const float* __restrict__ W_f, const float* __restrict__ W_c,
        const float* __restrict__ hidden, float* __restrict__ ws) {
    __shared__ float xs[256];
    int bx = blockIdx.x, t = threadIdx.x;
    if (bx < 128) {
        int g = bx & 3, kc = bx >> 2;
        int k0 = kc * 128;
        const float* Wm = (g == 0) ? W_i : (g == 1) ? W_o : (g == 2) ? W_f : W_c;
        const f32x4* p = (const f32x4*)(Wm + (size_t)k0 * Hh) + t;
        f32x4 a = (f32x4){0.f, 0.f, 0.f, 0.f};
#pragma unroll 8
        for (int k = k0; k < k0 + 128; ++k) {
            float x = (k < 1024) ? ws[WS_EMB + k] : (k < 3072) ? ws[WS_CTX + (k - 1024)] : hidden[k - 3072];
            f32x4 wv = __builtin_nontemporal_load(p);
            a += wv * x;
            p += 256;
        }
        *(f32x4*)&ws[WS_GATEP + (size_t)(g * 32 + kc) * 1024 + t * 4] = a;
    } else {
        int s = bx - 128;
        int kc = s / 50, vb = s % 50;
        int k0 = kc * 256;
        {
            int k = k0 + t;
            xs[t] = (k < 1024) ? ws[WS_EMB + k] : (k < 2048) ? hidden[k - 1024] : ws[WS_CTX + (k - 2048)];
        }
        __syncthreads();
        stream_wout(W_out, xs, k0, vb * 1024 + t * 4, ws + WS_PART_F + (size_t)kc * PP);
    }
}

__global__ __launch_bounds__(256) void kF(const float* __restrict__ b_i,
        const float* __restrict__ b_o, const float* __restrict__ b_f,
        const float* __restrict__ b_c, const float* __restrict__ cell,
        const float* __restrict__ b_out, float* __restrict__ ws, float* __restrict__ out) {
    int bx = blockIdx.x, t = threadIdx.x;
    if (bx < 197) {
        __shared__ float sm[256];
        int v = bx * 256 + t;
        float x = -INFINITY;
        if (v < Vv) {
            x = b_out[v];
            const float* pp = ws + WS_PART_F + v;
#pragma unroll
            for (int kc = 0; kc < 16; ++kc) x += pp[(size_t)kc * PP];
            ws[WS_LOG + v] = x;
        }
        sm[t] = x;
        __syncthreads();
        for (int off = 128; off > 0; off >>= 1) {
            if (t < off) sm[t] = fmaxf(sm[t], sm[t + off]);
            __syncthreads();
        }
        float m = sm[0];
        __syncthreads();
        sm[t] = (v < Vv) ? expf(x - m) : 0.f;
        __syncthreads();
        for (int off = 128; off > 0; off >>= 1) {
            if (t < off) sm[t] += sm[t + off];
            __syncthreads();
        }
        if (t == 0) { ws[WS_PAIR + 2 * bx] = m; ws[WS_PAIR + 2 * bx + 1] = sm[0]; }
    } else {
#pragma unroll
        for (int r = 0; r < 4; ++r) {
            int h = t + r * 256;
            float gp[4];
#pragma unroll
            for (int g = 0; g < 4; ++g) {
                float s = 0.f;
#pragma unroll 8
                for (int kc = 0; kc < 32; ++kc)
                    s += ws[WS_GATEP + (size_t)(g * 32 + kc) * 1024 + h];
                gp[g] = s;
            }
            float ig = sigmoidf_(gp[0] + b_i[h]);
            float og = sigmoidf_(gp[1] + b_o[h]);
            float fg = sigmoidf_(gp[2] + b_f[h]);
            float cg = tanhf(gp[3] + b_c[h]);
            float nc = fg * cell[h] + ig * cg;
            out[OUT_NC + h] = nc;
            out[OUT_NH + h] = og * tanhf(nc);
        }
    }
}

__global__ __launch_bounds__(256) void k8bc(const float* __restrict__ ws, float* __restrict__ out) {
    __shared__ float sm[256], ss[256];
    int t = threadIdx.x;
    float m = (t < 197) ? ws[WS_PAIR + 2 * t] : -INFINITY;
    float s = (t < 197) ? ws[WS_PAIR + 2 * t + 1] : 0.f;
    sm[t] = m;
    __syncthreads();
    for (int off = 128; off > 0; off >>= 1) {
        if (t < off) sm[t] = fmaxf(sm[t], sm[t + off]);
        __syncthreads();
    }
    float M = sm[0];
    ss[t] = s * expf(m - M);
    __syncthreads();
    for (int off = 128; off > 0; off >>= 1) {
        if (t < off) ss[t] += ss[t + off];
        __syncthreads();
    }
    float logZ = M + logf(ss[0]);
    int v = blockIdx.x * 256 + t;
    if (v < Vv) out[v] = ws[WS_LOG + v] - logZ;
}

extern "C" void kernel_launch(void* const* d_in, const int* in_sizes, int n_in,
                              void* d_out, int out_size, void* d_ws, size_t ws_size,
                              hipStream_t stream) {
    const int*   tok        = (const int*)d_in[0];
    const float* hidden     = (const float*)d_in[1];
    const float* enc        = (const float*)d_in[2];
    const float* cell       = (const float*)d_in[3];
    const float* W_emb      = (const float*)d_in[4];
    const float* b_emb      = (const float*)d_in[5];
    const float* W_attn     = (const float*)d_in[6];
    const float* b_attn     = (const float*)d_in[7];
    const float* W_attn_out = (const float*)d_in[8];
    // d_in[9] b_attn_out: softmax-invariant -> unused
    const float* W_i   = (const float*)d_in[10];
    const float* b_i   = (const float*)d_in[11];
    const float* W_o   = (const float*)d_in[12];
    const float* b_o   = (const float*)d_in[13];
    const float* W_f   = (const float*)d_in[14];
    const float* b_f   = (const float*)d_in[15];
    const float* W_c   = (const float*)d_in[16];
    const float* b_c   = (const float*)d_in[17];
    const float* W_out = (const float*)d_in[18];
    const float* b_out = (const float*)d_in[19];
    float* out = (float*)d_out;
    float* ws  = (float*)d_ws;
    char*  wsb = (char*)d_ws;

    int dev = 0, coop = 0;
    hipGetDevice(&dev);
    hipDeviceGetAttribute(&coop, hipDeviceAttributeCooperativeLaunch, dev);

    hipError_t err = hipErrorUnknown;
    if (coop) {
        void* args[] = {
            (void*)&tok, (void*)&hidden, (void*)&enc, (void*)&cell,
            (void*)&W_emb, (void*)&b_emb, (void*)&W_attn, (void*)&b_attn,
            (void*)&W_attn_out,
            (void*)&W_i, (void*)&b_i, (void*)&W_o, (void*)&b_o,
            (void*)&W_f, (void*)&b_f, (void*)&W_c, (void*)&b_c,
            (void*)&W_out, (void*)&b_out, (void*)&out, (void*)&ws, (void*)&wsb };
        err = hipLaunchCooperativeKernel((const void*)coopK, dim3(512), dim3(256),
                                         args, 0, stream);
    }
    if (err != hipSuccess) {
        kPrep<<<dim3(3340), dim3(256), 0, stream>>>(tok, W_emb, b_emb, enc, W_attn, hidden, ws, wsb);
        kG<<<dim3(512), dim3(128), 0, stream>>>(wsb, b_attn, W_attn_out, ws);
        k34<<<dim3(256), dim3(256), 0, stream>>>(enc, ws, out);
        kS<<<dim3(928), dim3(256), 0, stream>>>(W_out, W_i, W_o, W_f, W_c, hidden, ws);
        kF<<<dim3(198), dim3(256), 0, stream>>>(b_i, b_o, b_f, b_c, cell, b_out, ws, out);
        k8bc<<<dim3(197), dim3(256), 0, stream>>>(ws, out);
    }
}

// Round 11
// 217.077 us; speedup vs baseline: 2.4075x; 2.4075x over previous
//
#include <hip/hip_runtime.h>
#include <hip/hip_bf16.h>
#include <math.h>

#define Hh 1024
#define Vv 50257
#define Ll 2048
#define H2 2048
#define H4 4096

// ws float offsets
#define WS_EMB  0
#define WS_SC   1024
#define WS_CTX  3072
#define WS_GATE 5120
#define WS_LOG  9216
#define WS_PAIR 59474
// packed bf16 regions (byte offsets)
#define OA_BYTES 245760u     // A_pk: 2048x2048 bf16 = 8 MB
#define OB_BYTES 8634368u    // B_pk: 2048x1024 bf16 = 4 MB (ends float 3207168)
// hbias partials: 64 rows x 1024 floats (non-atomic), after packed regions
#define WS_HBP 3210240

// d_out layout (floats): [log_softmax 50257][next_hidden 1024][attn_weights 2048][new_cell 1024]
#define OUT_NH Vv
#define OUT_AW (Vv + 1024)
#define OUT_NC (Vv + 3072)

typedef __attribute__((ext_vector_type(8))) short bf16x8;
typedef __attribute__((ext_vector_type(4))) float f32x4;
typedef __attribute__((ext_vector_type(4), aligned(4))) float f32x4u;   // 4B-aligned vec4

__device__ __forceinline__ float sigmoidf_(float x) { return 1.f / (1.f + expf(-x)); }
__device__ __forceinline__ unsigned short f2bf(float f) {
    union { float f; unsigned u; } v; v.f = f;
    unsigned r = v.u + 0x7FFF + ((v.u >> 16) & 1);
    return (unsigned short)(r >> 16);
}

// ---- kPrep: packA (0..2047) | packB (2048..3071) | hbias partials (3072..3327)
//            | init emb/scores/ctx/gates/logits (3328..3560) ----
__global__ __launch_bounds__(256) void kPrep(const int* __restrict__ tok,
        const float* __restrict__ W_emb, const float* __restrict__ b_emb,
        const float* __restrict__ b_out, const float* __restrict__ enc,
        const float* __restrict__ W_attn, const float* __restrict__ hidden,
        float* __restrict__ ws, char* __restrict__ wsb) {
    __shared__ union { float a[16][132]; float b[32][68]; } sh;
    int bx = blockIdx.x, t = threadIdx.x;
    if (bx < 2048) {
        // ---- packA: enc fp32 -> A_pk bf16 fragment-ordered ----
        int mt = bx >> 4, kc = bx & 15;
        {
            int row = t >> 4, c8 = (t & 15) * 8;
            const float* src = enc + (size_t)(mt * 16 + row) * H2 + kc * 128 + c8;
            float4 v0 = *(const float4*)src;
            float4 v1 = *(const float4*)(src + 4);
            *(float4*)&sh.a[row][c8] = v0;
            *(float4*)&sh.a[row][c8 + 4] = v1;
        }
        __syncthreads();
        int ktl = t >> 6, l = t & 63;
        int r2 = l & 15, k8 = (l >> 4) * 8;
        bf16x8 o;
#pragma unroll
        for (int j = 0; j < 8; ++j) o[j] = (short)f2bf(sh.a[r2][ktl * 32 + k8 + j]);
        *(bf16x8*)(wsb + OA_BYTES + ((size_t)(mt * 64 + kc * 4 + ktl)) * 1024 + l * 16) = o;
    } else if (bx < 3072) {
        // ---- packB: W_attn[0:2048] -> B_pk bf16 fragment-ordered ----
        int bxx = bx - 2048;
        int kt = bxx >> 4, nc = bxx & 15;
        {
            int r = t >> 3, c8 = (t & 7) * 8;
            const float* src = W_attn + (size_t)(kt * 32 + r) * Hh + nc * 64 + c8;
            float4 v0 = *(const float4*)src;
            float4 v1 = *(const float4*)(src + 4);
            *(float4*)&sh.b[r][c8] = v0;
            *(float4*)&sh.b[r][c8 + 4] = v1;
        }
        __syncthreads();
        int ntl = t >> 6, l = t & 63;
        int col = ntl * 16 + (l & 15), k8 = (l >> 4) * 8;
        bf16x8 o;
#pragma unroll
        for (int j = 0; j < 8; ++j) o[j] = (short)f2bf(sh.b[k8 + j][col]);
        *(bf16x8*)(wsb + OB_BYTES + ((size_t)((nc * 4 + ntl) * 64 + kt)) * 1024 + l * 16) = o;
    } else if (bx < 3328) {
        // ---- hbias partials: hbp[kc][h] = sum_{16-chunk} hidden[k]*W_attn[2048+k][h]
        int bxx = bx - 3072;
        int hc = bxx & 3, kc = bxx >> 2;          // 4 hc x 64 kc (16 k each)
        int h = hc * 256 + t;
        int k0 = kc * 16;
        const float* p = W_attn + (size_t)(H2 + k0) * Hh + h;
        float acc = 0.f;
#pragma unroll
        for (int k = 0; k < 16; ++k) { acc += hidden[k0 + k] * __builtin_nontemporal_load(p); p += Hh; }
        ws[WS_HBP + kc * 1024 + h] = acc;
    } else {
        // ---- init ----
        int i = (bx - 3328) * 256 + t;            // 233 blocks -> 59648
        if (i < 1024)       ws[WS_EMB + i] = W_emb[(size_t)tok[0] * Hh + i] + b_emb[i];
        else if (i < 3072)  ws[WS_SC + (i - 1024)] = 0.f;
        else if (i < 5120)  ws[WS_CTX + (i - 3072)] = 0.f;
        else if (i < 9216)  ws[WS_GATE + (i - 5120)] = 0.f;
        else if (i < 59473) ws[WS_LOG + (i - 9216)] = b_out[i - 9216];
    }
}

// ---- kG: MFMA GEMM pre=A@B, fused tanh·Wo reduce -> atomic scores ----
// grid 512: bm 0..31, bn 0..15; 128 thr = 2 waves; 8-deep register prefetch ring
__global__ __launch_bounds__(128, 1) void kG(const char* __restrict__ wsb,
        const float* __restrict__ b_attn, const float* __restrict__ Wo,
        float* __restrict__ ws) {
    __shared__ float hbv[64];
    int bx = blockIdx.x;
    int bm = bx >> 4, bn = bx & 15;
    int t = threadIdx.x, w = t >> 6, l = t & 63;
    if (t < 64) {                                  // sum hbias partials for 64 n
        int n = bn * 64 + t;
        float a = b_attn[n];
#pragma unroll 16
        for (int kc = 0; kc < 64; ++kc) a += ws[WS_HBP + kc * 1024 + n];
        hbv[t] = a;
    }
    __syncthreads();
    int mt0 = bm * 4 + w * 2;
    int nt0 = bn * 4;
    const char* pa0 = wsb + OA_BYTES + (size_t)(mt0)     * 65536 + l * 16;
    const char* pa1 = wsb + OA_BYTES + (size_t)(mt0 + 1) * 65536 + l * 16;
    const char* pb0 = wsb + OB_BYTES + (size_t)(nt0)     * 65536 + l * 16;
    const char* pb1 = wsb + OB_BYTES + (size_t)(nt0 + 1) * 65536 + l * 16;
    const char* pb2 = wsb + OB_BYTES + (size_t)(nt0 + 2) * 65536 + l * 16;
    const char* pb3 = wsb + OB_BYTES + (size_t)(nt0 + 3) * 65536 + l * 16;

    f32x4 acc[2][4];
#pragma unroll
    for (int i = 0; i < 2; ++i)
#pragma unroll
        for (int j = 0; j < 4; ++j) acc[i][j] = (f32x4){0.f, 0.f, 0.f, 0.f};

    bf16x8 As[8][2], Bs[8][4];
#define LOADK(s, kk) { int o_ = (kk) * 1024; \
    As[s][0] = *(const bf16x8*)(pa0 + o_); As[s][1] = *(const bf16x8*)(pa1 + o_); \
    Bs[s][0] = *(const bf16x8*)(pb0 + o_); Bs[s][1] = *(const bf16x8*)(pb1 + o_); \
    Bs[s][2] = *(const bf16x8*)(pb2 + o_); Bs[s][3] = *(const bf16x8*)(pb3 + o_); }
#define MFMAK(s) { \
    _Pragma("unroll") for (int mr = 0; mr < 2; ++mr) \
    _Pragma("unroll") for (int nr = 0; nr < 4; ++nr) \
        acc[mr][nr] = __builtin_amdgcn_mfma_f32_16x16x32_bf16(As[s][mr], Bs[s][nr], acc[mr][nr], 0, 0, 0); }

    LOADK(0, 0) LOADK(1, 1) LOADK(2, 2) LOADK(3, 3)
    LOADK(4, 4) LOADK(5, 5) LOADK(6, 6) LOADK(7, 7)
    for (int kt = 0; kt < 56; kt += 8) {
        MFMAK(0) LOADK(0, kt + 8)
        MFMAK(1) LOADK(1, kt + 9)
        MFMAK(2) LOADK(2, kt + 10)
        MFMAK(3) LOADK(3, kt + 11)
        MFMAK(4) LOADK(4, kt + 12)
        MFMAK(5) LOADK(5, kt + 13)
        MFMAK(6) LOADK(6, kt + 14)
        MFMAK(7) LOADK(7, kt + 15)
    }
    MFMAK(0) MFMAK(1) MFMAK(2) MFMAK(3) MFMAK(4) MFMAK(5) MFMAK(6) MFMAK(7)
#undef LOADK
#undef MFMAK

    float sp[8];
#pragma unroll
    for (int i = 0; i < 8; ++i) sp[i] = 0.f;
    int nl = l & 15;
#pragma unroll
    for (int nr = 0; nr < 4; ++nr) {
        float hb = hbv[nr * 16 + nl];
        float wo = Wo[bn * 64 + nr * 16 + nl];
#pragma unroll
        for (int mr = 0; mr < 2; ++mr)
#pragma unroll
            for (int r = 0; r < 4; ++r)
                sp[mr * 4 + r] += tanhf(acc[mr][nr][r] + hb) * wo;
    }
#pragma unroll
    for (int m = 1; m <= 8; m <<= 1)
#pragma unroll
        for (int i = 0; i < 8; ++i) sp[i] += __shfl_xor(sp[i], m, 64);
    if ((l & 15) == 0) {
        int mbase = bm * 64 + w * 32 + (l >> 4) * 4;
#pragma unroll
        for (int mr = 0; mr < 2; ++mr)
#pragma unroll
            for (int r = 0; r < 4; ++r)
                atomicAdd(&ws[WS_SC + mbase + mr * 16 + r], sp[mr * 4 + r]);
    }
}

// ---- k34: fused softmax (redundant stats per block) + context ----
// grid 256 = 8 jc x 32 lc (64 l each); jc==0 blocks also write attn_weights out
__global__ __launch_bounds__(256) void k34(const float* __restrict__ enc,
        float* __restrict__ ws, float* __restrict__ out) {
    __shared__ float red[256];
    __shared__ float wl[64];
    int b = blockIdx.x, t = threadIdx.x;
    int jc = b & 7, lc = b >> 3;
    float s[8];
    float mx = -INFINITY;
#pragma unroll
    for (int i = 0; i < 8; ++i) { s[i] = ws[WS_SC + i * 256 + t]; mx = fmaxf(mx, s[i]); }
    red[t] = mx;
    __syncthreads();
    for (int off = 128; off > 0; off >>= 1) {
        if (t < off) red[t] = fmaxf(red[t], red[t + off]);
        __syncthreads();
    }
    float M = red[0];
    __syncthreads();
    float se = 0.f;
#pragma unroll
    for (int i = 0; i < 8; ++i) se += expf(s[i] - M);
    red[t] = se;
    __syncthreads();
    for (int off = 128; off > 0; off >>= 1) {
        if (t < off) red[t] += red[t + off];
        __syncthreads();
    }
    float invZ = 1.f / red[0];
    int l0 = lc * 64;
    if (t < 64) wl[t] = expf(ws[WS_SC + l0 + t] - M) * invZ;
    __syncthreads();
    if (jc == 0 && t < 64) out[OUT_AW + l0 + t] = wl[t];
    int j = jc * 256 + t;
    float acc = 0.f;
#pragma unroll 8
    for (int i = 0; i < 64; ++i)
        acc += wl[i] * enc[(size_t)(l0 + i) * H2 + j];
    atomicAdd(&ws[WS_CTX + j], acc);
}

// ---- k5k7: logits GEMV (0..799) | gate GEMVs (800..1311) ----
__global__ __launch_bounds__(256) void k5k7(const float* __restrict__ W_out,
        const float* __restrict__ W_i, const float* __restrict__ W_o,
        const float* __restrict__ W_f, const float* __restrict__ W_c,
        const float* __restrict__ hidden, float* __restrict__ ws) {
    int bx = blockIdx.x, t = threadIdx.x;
    if (bx < 800) {
        // ---- k7: 50 vb x 16 kc (256 k each), dwordx4 nontemporal stream ----
        __shared__ float xs[256];
        int vb = bx % 50, kc = bx / 50;
        int k0 = kc * 256;
        {
            int k = k0 + t;
            xs[t] = (k < 1024) ? ws[WS_EMB + k] : (k < 2048) ? hidden[k - 1024] : ws[WS_CTX + (k - 2048)];
        }
        __syncthreads();
        int v4 = vb * 1024 + t * 4;
        if (v4 + 3 < Vv) {
            const char* p = (const char*)(W_out + (size_t)k0 * Vv + v4);
            f32x4 a = (f32x4){0.f, 0.f, 0.f, 0.f};
#pragma unroll 4
            for (int i = 0; i < 256; ++i) {
                f32x4u wv = __builtin_nontemporal_load((const f32x4u*)p);
                a += wv * xs[i];
                p += (size_t)Vv * 4;
            }
            atomicAdd(&ws[WS_LOG + v4 + 0], a.x);
            atomicAdd(&ws[WS_LOG + v4 + 1], a.y);
            atomicAdd(&ws[WS_LOG + v4 + 2], a.z);
            atomicAdd(&ws[WS_LOG + v4 + 3], a.w);
        } else if (v4 < Vv) {
            for (int jj = 0; jj < 4 && v4 + jj < Vv; ++jj) {
                const float* p = W_out + (size_t)k0 * Vv + v4 + jj;
                float a = 0.f;
                for (int i = 0; i < 256; ++i) { a += xs[i] * (*p); p += Vv; }
                atomicAdd(&ws[WS_LOG + v4 + jj], a);
            }
        }
    } else {
        // ---- k5: 4 g x 128 kc (32 k each), float4 col per thread ----
        int bxx = bx - 800;
        int g = bxx & 3, kc = bxx >> 2;
        int k0 = kc * 32;
        const float* Wm = (g == 0) ? W_i : (g == 1) ? W_o : (g == 2) ? W_f : W_c;
        const f32x4* p = (const f32x4*)(Wm + (size_t)k0 * Hh) + t;
        f32x4 a = (f32x4){0.f, 0.f, 0.f, 0.f};
#pragma unroll 8
        for (int k = k0; k < k0 + 32; ++k) {
            float x = (k < 1024) ? ws[WS_EMB + k] : (k < 3072) ? ws[WS_CTX + (k - 1024)] : hidden[k - 3072];
            f32x4 wv = __builtin_nontemporal_load(p);
            a += wv * x;
            p += 256;
        }
        int h4 = t * 4;
        atomicAdd(&ws[WS_GATE + g * 1024 + h4 + 0], a.x);
        atomicAdd(&ws[WS_GATE + g * 1024 + h4 + 1], a.y);
        atomicAdd(&ws[WS_GATE + g * 1024 + h4 + 2], a.z);
        atomicAdd(&ws[WS_GATE + g * 1024 + h4 + 3], a.w);
    }
}

// ---- k6k8a: logit stats (0..196) | cell update (197) ----
__global__ __launch_bounds__(256) void k6k8a(const float* __restrict__ b_i,
        const float* __restrict__ b_o, const float* __restrict__ b_f,
        const float* __restrict__ b_c, const float* __restrict__ cell,
        float* __restrict__ ws, float* __restrict__ out) {
    int bx = blockIdx.x, t = threadIdx.x;
    if (bx < 197) {
        __shared__ float sm[256];
        int v = bx * 256 + t;
        float x = (v < Vv) ? ws[WS_LOG + v] : -INFINITY;
        sm[t] = x;
        __syncthreads();
        for (int off = 128; off > 0; off >>= 1) {
            if (t < off) sm[t] = fmaxf(sm[t], sm[t + off]);
            __syncthreads();
        }
        float m = sm[0];
        __syncthreads();
        sm[t] = (v < Vv) ? expf(x - m) : 0.f;
        __syncthreads();
        for (int off = 128; off > 0; off >>= 1) {
            if (t < off) sm[t] += sm[t + off];
            __syncthreads();
        }
        if (t == 0) { ws[WS_PAIR + 2 * bx] = m; ws[WS_PAIR + 2 * bx + 1] = sm[0]; }
    } else {
#pragma unroll
        for (int r = 0; r < 4; ++r) {
            int h = t + r * 256;
            float ig = sigmoidf_(ws[WS_GATE + h] + b_i[h]);
            float og = sigmoidf_(ws[WS_GATE + 1024 + h] + b_o[h]);
            float fg = sigmoidf_(ws[WS_GATE + 2048 + h] + b_f[h]);
            float cg = tanhf(ws[WS_GATE + 3072 + h] + b_c[h]);
            float nc = fg * cell[h] + ig * cg;
            out[OUT_NC + h] = nc;
            out[OUT_NH + h] = og * tanhf(nc);
        }
    }
}

// ---- k8bc: combine pairs (redundant per block) + write log_softmax ----
__global__ __launch_bounds__(256) void k8bc(const float* __restrict__ ws, float* __restrict__ out) {
    __shared__ float sm[256], ss[256];
    int t = threadIdx.x;
    float m = (t < 197) ? ws[WS_PAIR + 2 * t] : -INFINITY;
    float s = (t < 197) ? ws[WS_PAIR + 2 * t + 1] : 0.f;
    sm[t] = m;
    __syncthreads();
    for (int off = 128; off > 0; off >>= 1) {
        if (t < off) sm[t] = fmaxf(sm[t], sm[t + off]);
        __syncthreads();
    }
    float M = sm[0];
    ss[t] = s * expf(m - M);
    __syncthreads();
    for (int off = 128; off > 0; off >>= 1) {
        if (t < off) ss[t] += ss[t + off];
        __syncthreads();
    }
    float logZ = M + logf(ss[0]);
    int v = blockIdx.x * 256 + t;
    if (v < Vv) out[v] = ws[WS_LOG + v] - logZ;
}

extern "C" void kernel_launch(void* const* d_in, const int* in_sizes, int n_in,
                              void* d_out, int out_size, void* d_ws, size_t ws_size,
                              hipStream_t stream) {
    const int*   tok        = (const int*)d_in[0];
    const float* hidden     = (const float*)d_in[1];
    const float* enc        = (const float*)d_in[2];
    const float* cell       = (const float*)d_in[3];
    const float* W_emb      = (const float*)d_in[4];
    const float* b_emb      = (const float*)d_in[5];
    const float* W_attn     = (const float*)d_in[6];
    const float* b_attn     = (const float*)d_in[7];
    const float* W_attn_out = (const float*)d_in[8];
    // d_in[9] b_attn_out: softmax-invariant -> unused
    const float* W_i   = (const float*)d_in[10];
    const float* b_i   = (const float*)d_in[11];
    const float* W_o   = (const float*)d_in[12];
    const float* b_o   = (const float*)d_in[13];
    const float* W_f   = (const float*)d_in[14];
    const float* b_f   = (const float*)d_in[15];
    const float* W_c   = (const float*)d_in[16];
    const float* b_c   = (const float*)d_in[17];
    const float* W_out = (const float*)d_in[18];
    const float* b_out = (const float*)d_in[19];
    float* out = (float*)d_out;
    float* ws  = (float*)d_ws;
    char*  wsb = (char*)d_ws;

    kPrep<<<dim3(3561), dim3(256), 0, stream>>>(tok, W_emb, b_emb, b_out, enc, W_attn, hidden, ws, wsb);
    kG<<<dim3(512), dim3(128), 0, stream>>>(wsb, b_attn, W_attn_out, ws);
    k34<<<dim3(256), dim3(256), 0, stream>>>(enc, ws, out);
    k5k7<<<dim3(1312), dim3(256), 0, stream>>>(W_out, W_i, W_o, W_f, W_c, hidden, ws);
    k6k8a<<<dim3(198), dim3(256), 0, stream>>>(b_i, b_o, b_f, b_c, cell, ws, out);
    k8bc<<<dim3(197), dim3(256), 0, stream>>>(ws, out);
}